// Round 5
// baseline (1197.086 us; speedup 1.0000x reference)
//
#include <hip/hip_runtime.h>

// Trilinear gridding via counting-sort for atomic locality.
//   B=32, N=65536, scale=128 -> s=64, G=128, out = 32 x 128^3 f32 (256 MB).
// Naive version was atomic-RMW-latency bound (815us, WRITE_SIZE 524MB = grid
// evicted ~2x, 90% L2 miss on random atomics). Fix: counting-sort points by
// (batch, 8^3-cell coarse bin) so consecutive threads' atomics hit resident
// L2 lines; grid then streams out ~once.

#define BLK 256
#define NBINS_MAX 131072                 // 32 batches * (128/8)^3 bins
#define SCAN_CHUNK 256
#define NCHUNK (NBINS_MAX / SCAN_CHUNK)  // 512

// d_ws byte layout
#define HIST_OFF    0
#define PREFIX_OFF  ((size_t)NBINS_MAX * 4)
#define CURSOR_OFF  ((size_t)NBINS_MAX * 8)
#define PART_OFF    ((size_t)NBINS_MAX * 12)
#define PARTEXC_OFF ((size_t)NBINS_MAX * 12 + (size_t)NCHUNK * 4)
#define TOTAL_OFF   ((size_t)NBINS_MAX * 12 + (size_t)NCHUNK * 8)
#define SORTED_OFF  ((size_t)2 * 1024 * 1024)

__global__ void zero_kernel(float4* __restrict__ out, int n4) {
    int i = blockIdx.x * blockDim.x + threadIdx.x;
    const int stride = gridDim.x * blockDim.x;
    for (; i < n4; i += stride) out[i] = float4{0.f, 0.f, 0.f, 0.f};
}

__device__ __forceinline__ bool point_geom(const float* pts, const int* scale_p,
                                           int i, int total_pts, int out_size,
                                           float& x, float& y, float& z,
                                           int& bin, int& b) {
    const int scale = scale_p[0];
    const int s = scale >> 1;
    const int G = 2 * s;
    const int C = G >> 3;                 // coarse bins per axis (8^3 cells each)
    const int B = out_size / (G * G * G);
    const int N = total_pts / B;
    const float fs = (float)s;
    x = pts[3 * i + 0] * fs;
    y = pts[3 * i + 1] * fs;
    z = pts[3 * i + 2] * fs;
    if (x + y + z == 0.0f) return false;  // reference mask
    const int ix = (int)floorf(x) + s;
    const int iy = (int)floorf(y) + s;
    const int iz = (int)floorf(z) + s;
    b = i / N;
    bin = ((b * C + (ix >> 3)) * C + (iy >> 3)) * C + (iz >> 3);
    return true;
}

__global__ void hist_kernel(const float* __restrict__ pts, const int* __restrict__ scale_p,
                            int* __restrict__ hist, int total_pts, int out_size) {
    int i = blockIdx.x * blockDim.x + threadIdx.x;
    if (i >= total_pts) return;
    float x, y, z; int bin, b;
    if (!point_geom(pts, scale_p, i, total_pts, out_size, x, y, z, bin, b)) return;
    atomicAdd(hist + bin, 1);
}

__global__ void scan_partial(const int* __restrict__ hist, int* __restrict__ partial) {
    __shared__ int red[BLK / 64];
    int i = blockIdx.x * BLK + threadIdx.x;
    int v = hist[i];
    for (int o = 32; o > 0; o >>= 1) v += __shfl_down(v, o);
    if ((threadIdx.x & 63) == 0) red[threadIdx.x >> 6] = v;
    __syncthreads();
    if (threadIdx.x == 0) {
        int t = 0;
        for (int w = 0; w < BLK / 64; ++w) t += red[w];
        partial[blockIdx.x] = t;
    }
}

__global__ void scan_top(const int* __restrict__ partial, int* __restrict__ partExc,
                         int* __restrict__ total) {
    __shared__ int sm[NCHUNK];
    const int t = threadIdx.x;            // blockDim.x == NCHUNK == 512
    sm[t] = partial[t];
    __syncthreads();
    for (int o = 1; o < NCHUNK; o <<= 1) {
        int v = (t >= o) ? sm[t - o] : 0;
        __syncthreads();
        sm[t] += v;
        __syncthreads();
    }
    partExc[t] = (t == 0) ? 0 : sm[t - 1];
    if (t == NCHUNK - 1) *total = sm[t];
}

__global__ void scan_chunks(const int* __restrict__ hist, const int* __restrict__ partExc,
                            int* __restrict__ prefix, int* __restrict__ cursor) {
    __shared__ int sm[SCAN_CHUNK];
    const int t = threadIdx.x;
    const int base = blockIdx.x * SCAN_CHUNK;
    sm[t] = hist[base + t];
    __syncthreads();
    for (int o = 1; o < SCAN_CHUNK; o <<= 1) {
        int v = (t >= o) ? sm[t - o] : 0;
        __syncthreads();
        sm[t] += v;
        __syncthreads();
    }
    const int exc = ((t == 0) ? 0 : sm[t - 1]) + partExc[blockIdx.x];
    prefix[base + t] = exc;
    cursor[base + t] = exc;
}

__global__ void scatter_kernel(const float* __restrict__ pts, const int* __restrict__ scale_p,
                               int* __restrict__ cursor, float4* __restrict__ sorted,
                               int total_pts, int out_size) {
    int i = blockIdx.x * blockDim.x + threadIdx.x;
    if (i >= total_pts) return;
    float x, y, z; int bin, b;
    if (!point_geom(pts, scale_p, i, total_pts, out_size, x, y, z, bin, b)) return;
    const int pos = atomicAdd(cursor + bin, 1);
    sorted[pos] = make_float4(x, y, z, (float)b);   // pre-scaled coords
}

__global__ void grid_kernel(const float4* __restrict__ sorted, const int* __restrict__ scale_p,
                            const int* __restrict__ total, float* __restrict__ out,
                            int total_pts, int out_size) {
    int j = blockIdx.x * blockDim.x + threadIdx.x;
    if (j >= *total) return;
    const int scale = scale_p[0];
    const int s = scale >> 1;
    const int G = 2 * s;
    const float4 q = sorted[j];

    const float flx = floorf(q.x), fly = floorf(q.y), flz = floorf(q.z);
    const float ax = q.x - flx, ay = q.y - fly, az = q.z - flz;
    const int ix = (int)flx + s;
    const int iy = (int)fly + s;
    const int iz = (int)flz + s;
    const int b = (int)q.w;

    const float wx[2] = {1.0f - ax, ax};
    const float wy[2] = {1.0f - ay, ay};
    const float wz[2] = {1.0f - az, az};

    float* g = out + (size_t)b * (size_t)(G * G * G);
    const int base = (ix * G + iy) * G + iz;

#pragma unroll
    for (int dx = 0; dx < 2; ++dx)
#pragma unroll
        for (int dy = 0; dy < 2; ++dy)
#pragma unroll
            for (int dz = 0; dz < 2; ++dz)
                atomicAdd(&g[base + (dx * G + dy) * G + dz], wx[dx] * wy[dy] * wz[dz]);
}

// Fallback (ws too small): naive one-thread-per-point scatter.
__global__ void naive_kernel(const float* __restrict__ pts, const int* __restrict__ scale_p,
                             float* __restrict__ out, int total_pts, int out_size) {
    int i = blockIdx.x * blockDim.x + threadIdx.x;
    if (i >= total_pts) return;
    float x, y, z; int bin, b;
    if (!point_geom(pts, scale_p, i, total_pts, out_size, x, y, z, bin, b)) return;
    const int scale = scale_p[0];
    const int s = scale >> 1;
    const int G = 2 * s;
    const float flx = floorf(x), fly = floorf(y), flz = floorf(z);
    const float ax = x - flx, ay = y - fly, az = z - flz;
    const int ix = (int)flx + s, iy = (int)fly + s, iz = (int)flz + s;
    const float wx[2] = {1.0f - ax, ax};
    const float wy[2] = {1.0f - ay, ay};
    const float wz[2] = {1.0f - az, az};
    float* g = out + (size_t)b * (size_t)(G * G * G);
    const int base = (ix * G + iy) * G + iz;
#pragma unroll
    for (int dx = 0; dx < 2; ++dx)
#pragma unroll
        for (int dy = 0; dy < 2; ++dy)
#pragma unroll
            for (int dz = 0; dz < 2; ++dz)
                atomicAdd(&g[base + (dx * G + dy) * G + dz], wx[dx] * wy[dy] * wz[dz]);
}

extern "C" void kernel_launch(void* const* d_in, const int* in_sizes, int n_in,
                              void* d_out, int out_size, void* d_ws, size_t ws_size,
                              hipStream_t stream) {
    const float* pts = (const float*)d_in[0];
    const int* scale_p = (const int*)d_in[1];
    float* out = (float*)d_out;
    char* ws = (char*)d_ws;

    const int total_pts = in_sizes[0] / 3;
    const int pt_blocks = (total_pts + BLK - 1) / BLK;

    // zero the grid (harness poisons d_out with 0xAA each launch)
    zero_kernel<<<2048, BLK, 0, stream>>>((float4*)d_out, out_size / 4);

    const size_t need = SORTED_OFF + (size_t)total_pts * 16;
    if (ws_size < need) {
        naive_kernel<<<pt_blocks, BLK, 0, stream>>>(pts, scale_p, out, total_pts, out_size);
        return;
    }

    int* hist    = (int*)(ws + HIST_OFF);
    int* prefix  = (int*)(ws + PREFIX_OFF);
    int* cursor  = (int*)(ws + CURSOR_OFF);
    int* partial = (int*)(ws + PART_OFF);
    int* partExc = (int*)(ws + PARTEXC_OFF);
    int* total   = (int*)(ws + TOTAL_OFF);
    float4* sorted = (float4*)(ws + SORTED_OFF);

    hipMemsetAsync(hist, 0, (size_t)NBINS_MAX * 4, stream);
    hist_kernel<<<pt_blocks, BLK, 0, stream>>>(pts, scale_p, hist, total_pts, out_size);
    scan_partial<<<NCHUNK, BLK, 0, stream>>>(hist, partial);
    scan_top<<<1, NCHUNK, 0, stream>>>(partial, partExc, total);
    scan_chunks<<<NCHUNK, SCAN_CHUNK, 0, stream>>>(hist, partExc, prefix, cursor);
    scatter_kernel<<<pt_blocks, BLK, 0, stream>>>(pts, scale_p, cursor, sorted, total_pts, out_size);
    grid_kernel<<<pt_blocks, BLK, 0, stream>>>(sorted, scale_p, total, out, total_pts, out_size);
}

// Round 6
// 528.446 us; speedup vs baseline: 2.2653x; 2.2653x over previous
//
#include <hip/hip_runtime.h>

// Trilinear gridding, owner-computes formulation (zero global atomics):
//   B=32, N=65536, scale=128 -> s=64, G=128, out = 32 x 128^3 f32 (256 MB).
// Round-4/5 lesson: global f32 atomics cost ~32B HBM write-beat each
// (WRITE_SIZE ~= n_atomics*32B regardless of target locality) and are
// latency-bound at ~23 G/s -> 725-815us. Fix: counting-sort points by
// (batch, 4x4x32-cell tile); one 64-thread block OWNS each 4x4x32 vertex
// tile, gathers candidate points from its 8 lower-neighbor bins, accumulates
// in LDS (fast ds_add atomics), and writes the tile with plain coalesced
// stores -- each output cache line written exactly once. No zeroing pass
// needed: every vertex is stored unconditionally.

#define BLK 256
#define NBINS 131072                     // 32 batches * 32*32*4 tiles
#define SCAN_CHUNK 256
#define NCHUNK (NBINS / SCAN_CHUNK)      // 512
// tile geometry (vertices / cells per bin): 4 x 4 x 32
#define RX 4
#define RY 4
#define RZ 32

// d_ws byte layout
#define HIST_OFF    0
#define PREFIX_OFF  ((size_t)NBINS * 4)
#define CURSOR_OFF  ((size_t)NBINS * 8)   // after scatter, cursor[bin] == end
#define PART_OFF    ((size_t)NBINS * 12)
#define PARTEXC_OFF ((size_t)NBINS * 12 + (size_t)NCHUNK * 4)
#define SORTED_OFF  ((size_t)2 * 1024 * 1024)

__global__ void zero_kernel(float4* __restrict__ out, int n4) {
    int i = blockIdx.x * blockDim.x + threadIdx.x;
    const int stride = gridDim.x * blockDim.x;
    for (; i < n4; i += stride) out[i] = float4{0.f, 0.f, 0.f, 0.f};
}

__device__ __forceinline__ bool point_geom(const float* pts, const int* scale_p,
                                           int i, int total_pts, int out_size,
                                           float& x, float& y, float& z,
                                           int& bin, int& b) {
    const int scale = scale_p[0];
    const int s = scale >> 1;
    const int G = 2 * s;
    const int CX = G / RX, CY = G / RY, CZ = G / RZ;
    const int B = out_size / (G * G * G);
    const int N = total_pts / B;
    const float fs = (float)s;
    x = pts[3 * i + 0] * fs;
    y = pts[3 * i + 1] * fs;
    z = pts[3 * i + 2] * fs;
    if (x + y + z == 0.0f) return false;  // reference mask
    const int cx = (int)floorf(x) + s;    // cell = lower-corner vertex index
    const int cy = (int)floorf(y) + s;
    const int cz = (int)floorf(z) + s;
    b = i / N;
    bin = ((b * CX + (cx / RX)) * CY + (cy / RY)) * CZ + (cz / RZ);
    return true;
}

__global__ void hist_kernel(const float* __restrict__ pts, const int* __restrict__ scale_p,
                            int* __restrict__ hist, int total_pts, int out_size) {
    int i = blockIdx.x * blockDim.x + threadIdx.x;
    if (i >= total_pts) return;
    float x, y, z; int bin, b;
    if (!point_geom(pts, scale_p, i, total_pts, out_size, x, y, z, bin, b)) return;
    atomicAdd(hist + bin, 1);
}

__global__ void scan_partial(const int* __restrict__ hist, int* __restrict__ partial) {
    __shared__ int red[BLK / 64];
    int i = blockIdx.x * BLK + threadIdx.x;
    int v = hist[i];
    for (int o = 32; o > 0; o >>= 1) v += __shfl_down(v, o);
    if ((threadIdx.x & 63) == 0) red[threadIdx.x >> 6] = v;
    __syncthreads();
    if (threadIdx.x == 0) {
        int t = 0;
        for (int w = 0; w < BLK / 64; ++w) t += red[w];
        partial[blockIdx.x] = t;
    }
}

__global__ void scan_top(const int* __restrict__ partial, int* __restrict__ partExc) {
    __shared__ int sm[NCHUNK];
    const int t = threadIdx.x;            // blockDim.x == NCHUNK == 512
    sm[t] = partial[t];
    __syncthreads();
    for (int o = 1; o < NCHUNK; o <<= 1) {
        int v = (t >= o) ? sm[t - o] : 0;
        __syncthreads();
        sm[t] += v;
        __syncthreads();
    }
    partExc[t] = (t == 0) ? 0 : sm[t - 1];
}

__global__ void scan_chunks(const int* __restrict__ hist, const int* __restrict__ partExc,
                            int* __restrict__ prefix, int* __restrict__ cursor) {
    __shared__ int sm[SCAN_CHUNK];
    const int t = threadIdx.x;
    const int base = blockIdx.x * SCAN_CHUNK;
    sm[t] = hist[base + t];
    __syncthreads();
    for (int o = 1; o < SCAN_CHUNK; o <<= 1) {
        int v = (t >= o) ? sm[t - o] : 0;
        __syncthreads();
        sm[t] += v;
        __syncthreads();
    }
    const int exc = ((t == 0) ? 0 : sm[t - 1]) + partExc[blockIdx.x];
    prefix[base + t] = exc;
    cursor[base + t] = exc;
}

__global__ void scatter_kernel(const float* __restrict__ pts, const int* __restrict__ scale_p,
                               int* __restrict__ cursor, float4* __restrict__ sorted,
                               int total_pts, int out_size) {
    int i = blockIdx.x * blockDim.x + threadIdx.x;
    if (i >= total_pts) return;
    float x, y, z; int bin, b;
    if (!point_geom(pts, scale_p, i, total_pts, out_size, x, y, z, bin, b)) return;
    const int pos = atomicAdd(cursor + bin, 1);
    sorted[pos] = make_float4(x, y, z, (float)b);   // pre-scaled coords
}

// One 64-thread block per (batch, 4x4x32 vertex tile). Gather candidate
// points from the <=8 lower-neighbor bins, accumulate in LDS, store tile.
__global__ void __launch_bounds__(64) gather_kernel(
        const float4* __restrict__ sorted, const int* __restrict__ prefix,
        const int* __restrict__ binEnd, const int* __restrict__ scale_p,
        float* __restrict__ out, int out_size) {
    const int scale = scale_p[0];
    const int s = scale >> 1;
    const int G = 2 * s;
    const int CX = G / RX, CY = G / RY, CZ = G / RZ;

    int id = blockIdx.x;
    const int bz = id % CZ; id /= CZ;
    const int by = id % CY; id /= CY;
    const int bx = id % CX;
    const int b  = id / CX;

    const int X0 = bx * RX, Y0 = by * RY, Z0 = bz * RZ;
    const int lane = threadIdx.x;

    __shared__ float tile[RX * RY * RZ];  // 512 floats, 2 KB
#pragma unroll
    for (int k = 0; k < (RX * RY * RZ) / 64; ++k)
        tile[lane + 64 * k] = 0.0f;
    __syncthreads();

    // candidate bins: {bx-1,bx} x {by-1,by} x contiguous z range [bz-1, bz]
    const int zlo = (bz > 0) ? bz - 1 : 0;
#pragma unroll
    for (int ex = 0; ex < 2; ++ex) {
        const int xb = bx - 1 + ex;
        if (xb < 0 || xb >= CX) continue;
#pragma unroll
        for (int ey = 0; ey < 2; ++ey) {
            const int yb = by - 1 + ey;
            if (yb < 0 || yb >= CY) continue;
            const int binLo = ((b * CX + xb) * CY + yb) * CZ + zlo;
            const int binHi = ((b * CX + xb) * CY + yb) * CZ + bz;
            const int start = prefix[binLo];
            const int end   = binEnd[binHi];
            for (int j = start + lane; j < end; j += 64) {
                const float4 q = sorted[j];
                const float flx = floorf(q.x), fly = floorf(q.y), flz = floorf(q.z);
                const int ix = (int)flx + s;
                const int iy = (int)fly + s;
                const int iz = (int)flz + s;
                // corners ix..ix+1 must intersect [X0,X0+RX) etc.
                if (ix < X0 - 1 || ix > X0 + RX - 1 ||
                    iy < Y0 - 1 || iy > Y0 + RY - 1 ||
                    iz < Z0 - 1 || iz > Z0 + RZ - 1) continue;
                const float ax = q.x - flx, ay = q.y - fly, az = q.z - flz;
                const float wx[2] = {1.0f - ax, ax};
                const float wy[2] = {1.0f - ay, ay};
                const float wz[2] = {1.0f - az, az};
#pragma unroll
                for (int dx = 0; dx < 2; ++dx) {
                    const int vx = ix + dx - X0;
                    if ((unsigned)vx >= RX) continue;
#pragma unroll
                    for (int dy = 0; dy < 2; ++dy) {
                        const int vy = iy + dy - Y0;
                        if ((unsigned)vy >= RY) continue;
#pragma unroll
                        for (int dz = 0; dz < 2; ++dz) {
                            const int vz = iz + dz - Z0;
                            if ((unsigned)vz >= RZ) continue;
                            atomicAdd(&tile[(vx * RY + vy) * RZ + vz],
                                      wx[dx] * wy[dy] * wz[dz]);
                        }
                    }
                }
            }
        }
    }
    __syncthreads();

    // store tile: lane t writes 8 consecutive floats (2x float4), lines owned
    // exclusively by this block -> each 128B line written exactly once.
    const int l = lane * 8;
    const int vx = l >> 7, vy = (l >> 5) & 3, vzb = l & 31;
    float* dst = out + (size_t)b * (size_t)(G * G * G)
                     + ((size_t)(X0 + vx) * G + (Y0 + vy)) * G + Z0 + vzb;
    const float4* src = (const float4*)&tile[l];
    ((float4*)dst)[0] = src[0];
    ((float4*)dst)[1] = src[1];
}

// Fallback: naive one-thread-per-point scatter (needs zeroed out).
__global__ void naive_kernel(const float* __restrict__ pts, const int* __restrict__ scale_p,
                             float* __restrict__ out, int total_pts, int out_size) {
    int i = blockIdx.x * blockDim.x + threadIdx.x;
    if (i >= total_pts) return;
    float x, y, z; int bin, b;
    if (!point_geom(pts, scale_p, i, total_pts, out_size, x, y, z, bin, b)) return;
    const int scale = scale_p[0];
    const int s = scale >> 1;
    const int G = 2 * s;
    const float flx = floorf(x), fly = floorf(y), flz = floorf(z);
    const float ax = x - flx, ay = y - fly, az = z - flz;
    const int ix = (int)flx + s, iy = (int)fly + s, iz = (int)flz + s;
    const float wx[2] = {1.0f - ax, ax};
    const float wy[2] = {1.0f - ay, ay};
    const float wz[2] = {1.0f - az, az};
    float* g = out + (size_t)b * (size_t)(G * G * G);
    const int base = (ix * G + iy) * G + iz;
#pragma unroll
    for (int dx = 0; dx < 2; ++dx)
#pragma unroll
        for (int dy = 0; dy < 2; ++dy)
#pragma unroll
            for (int dz = 0; dz < 2; ++dz)
                atomicAdd(&g[base + (dx * G + dy) * G + dz], wx[dx] * wy[dy] * wz[dz]);
}

extern "C" void kernel_launch(void* const* d_in, const int* in_sizes, int n_in,
                              void* d_out, int out_size, void* d_ws, size_t ws_size,
                              hipStream_t stream) {
    const float* pts = (const float*)d_in[0];
    const int* scale_p = (const int*)d_in[1];
    float* out = (float*)d_out;
    char* ws = (char*)d_ws;

    const int total_pts = in_sizes[0] / 3;
    const int pt_blocks = (total_pts + BLK - 1) / BLK;

    const size_t need = SORTED_OFF + (size_t)total_pts * 16;
    // Owner-computes path assumes the benchmark shape (grid sizes hard-coded
    // to NBINS); fall back otherwise.
    const bool std_shape = (out_size == 32 * 128 * 128 * 128) &&
                           (total_pts == 32 * 65536) && (ws_size >= need);
    if (!std_shape) {
        zero_kernel<<<2048, BLK, 0, stream>>>((float4*)d_out, out_size / 4);
        naive_kernel<<<pt_blocks, BLK, 0, stream>>>(pts, scale_p, out, total_pts, out_size);
        return;
    }

    int* hist    = (int*)(ws + HIST_OFF);
    int* prefix  = (int*)(ws + PREFIX_OFF);
    int* cursor  = (int*)(ws + CURSOR_OFF);
    int* partial = (int*)(ws + PART_OFF);
    int* partExc = (int*)(ws + PARTEXC_OFF);
    float4* sorted = (float4*)(ws + SORTED_OFF);

    hipMemsetAsync(hist, 0, (size_t)NBINS * 4, stream);
    hist_kernel<<<pt_blocks, BLK, 0, stream>>>(pts, scale_p, hist, total_pts, out_size);
    scan_partial<<<NCHUNK, BLK, 0, stream>>>(hist, partial);
    scan_top<<<1, NCHUNK, 0, stream>>>(partial, partExc);
    scan_chunks<<<NCHUNK, SCAN_CHUNK, 0, stream>>>(hist, partExc, prefix, cursor);
    scatter_kernel<<<pt_blocks, BLK, 0, stream>>>(pts, scale_p, cursor, sorted, total_pts, out_size);
    // after scatter, cursor[bin] == prefix[bin] + hist[bin] == end of bin
    gather_kernel<<<NBINS, 64, 0, stream>>>(sorted, prefix, cursor, scale_p, out, out_size);
}